// Round 9
// baseline (77.136 us; speedup 1.0000x reference)
//
#include <hip/hip_runtime.h>
#include <hip/hip_bf16.h>
#include <math.h>

#define BATCH 4
#define CH    256
#define NPOS  4096
#define DQK   32
#define SHIFT 20.0f

typedef __attribute__((ext_vector_type(8))) short bf16x8;
typedef __attribute__((ext_vector_type(4))) float f32x4;

static __device__ __forceinline__ unsigned int pack_bf2(float a, float b) {
    __hip_bfloat162 h = __float22bfloat162_rn(make_float2(a, b));
    return *reinterpret_cast<unsigned int*>(&h);
}
static __device__ __forceinline__ unsigned short f2bf1(float f) {
    unsigned int u = __float_as_uint(f);
    u += 0x7fff + ((u >> 16) & 1);
    return (unsigned short)(u >> 16);
}
static __device__ __forceinline__ bf16x8 pack8(const float* v) {
    bf16x8 r;
    #pragma unroll
    for (int j = 0; j < 8; ++j) r[j] = (short)f2bf1(v[j]);
    return r;
}

// Barrier WITHOUT the vmcnt(0) drain: LDS ops must be complete (cross-wave
// visibility), but register-destined global prefetches stay in flight.
static __device__ __forceinline__ void lds_barrier() {
    asm volatile("s_waitcnt lgkmcnt(0)" ::: "memory");
    __builtin_amdgcn_s_barrier();
    asm volatile("" ::: "memory");
}

// ---------------- Kernel 1: MFMA projection GEMM (unchanged) ----------------
__global__ __launch_bounds__(256) void qkv_proj_mfma(
    const float* __restrict__ x,
    const float* __restrict__ Wq, const float* __restrict__ bq,
    const float* __restrict__ Wk, const float* __restrict__ bk,
    const float* __restrict__ Wv, const float* __restrict__ bv,
    __hip_bfloat16* __restrict__ qb, __hip_bfloat16* __restrict__ kb,
    __hip_bfloat16* __restrict__ vb)
{
    const int tid  = threadIdx.x;
    const int wave = tid >> 6, lane = tid & 63;
    const int g    = lane >> 4, lm = lane & 15;
    const int n0   = blockIdx.x * 32;
    const int b    = blockIdx.y;
    const float* xb = x + (size_t)b * CH * NPOS;

    bf16x8 xf[2][8];
    #pragma unroll
    for (int nt = 0; nt < 2; ++nt)
        #pragma unroll
        for (int kt = 0; kt < 8; ++kt) {
            const float* p = xb + (32 * kt + 8 * g) * NPOS + n0 + 16 * nt + lm;
            float v[8];
            #pragma unroll
            for (int j = 0; j < 8; ++j) v[j] = p[j * NPOS];
            xf[nt][kt] = pack8(v);
        }

    #pragma unroll
    for (int s = 0; s < 5; ++s) {
        const int cot = wave * 5 + s;
        const float* Wsrc; const float* bsrc; int cbase; int kind;
        if (cot < 2)      { Wsrc = Wq; bsrc = bq; cbase = cot * 16;      kind = 0; }
        else if (cot < 4) { Wsrc = Wk; bsrc = bk; cbase = cot * 16 - 32; kind = 1; }
        else              { Wsrc = Wv; bsrc = bv; cbase = cot * 16 - 64; kind = 2; }

        bf16x8 wf[8];
        const float* wrow = Wsrc + (size_t)(cbase + lm) * CH;
        #pragma unroll
        for (int kt = 0; kt < 8; ++kt) {
            float4 wa = *(const float4*)(wrow + 32 * kt + 8 * g);
            float4 wc = *(const float4*)(wrow + 32 * kt + 8 * g + 4);
            float wv[8] = {wa.x, wa.y, wa.z, wa.w, wc.x, wc.y, wc.z, wc.w};
            wf[kt] = pack8(wv);
        }
        const float4 b4 = *(const float4*)(bsrc + cbase + 4 * g);
        f32x4 a0 = {b4.x, b4.y, b4.z, b4.w};
        f32x4 a1 = a0;
        #pragma unroll
        for (int kt = 0; kt < 8; ++kt) {
            a0 = __builtin_amdgcn_mfma_f32_16x16x32_bf16(wf[kt], xf[0][kt], a0, 0, 0, 0);
            a1 = __builtin_amdgcn_mfma_f32_16x16x32_bf16(wf[kt], xf[1][kt], a1, 0, 0, 0);
        }

        if (kind <= 1) {
            __hip_bfloat16* dst = (kind == 0 ? qb : kb);
            #pragma unroll
            for (int nt = 0; nt < 2; ++nt) {
                f32x4 a = nt ? a1 : a0;
                int n = n0 + 16 * nt + lm;
                uint2 w;
                w.x = pack_bf2(a[0], a[1]);
                w.y = pack_bf2(a[2], a[3]);
                *(uint2*)(dst + ((size_t)b * NPOS + n) * DQK + cbase + 4 * g) = w;
            }
        } else {
            #pragma unroll
            for (int nt = 0; nt < 2; ++nt) {
                f32x4 a = nt ? a1 : a0;
                int n = n0 + 16 * nt + lm;
                int n64 = n >> 6, half = (n >> 5) & 1, nin = n & 31;
                #pragma unroll
                for (int r = 0; r < 4; ++r) {
                    int c = cbase + 4 * g + r;
                    size_t off = (((size_t)b * 16 + (c >> 4)) * 64 + n64) * 1024
                               + (size_t)half * 512 + (c & 15) * 32 + nin;
                    *reinterpret_cast<unsigned short*>(vb + off) = f2bf1(a[r]);
                }
            }
        }
    }
}

// ---------------- Kernel 2: cooperative MFMA flash, 2 key-tiles per phase ----------------
// grid 256: b = bid&3 (one batch per XCD), mblk = bid>>2 -> 64 m-rows/block.
// block 512 = 8 waves. Phase p: PV(2p,2p+1) from Pbuf[p&1]  ||  QK(2p+2,2p+3)
// -> Pbuf[(p+1)&1]; V prefetched 1 phase ahead, K 2 phases ahead (registers,
// survive the lgkmcnt-only barrier). 32 barriers total.
__global__ __launch_bounds__(512) void flash_pam_kernel(
    const __hip_bfloat16* __restrict__ qb, const __hip_bfloat16* __restrict__ kb,
    const __hip_bfloat16* __restrict__ vb, const float* __restrict__ x,
    const float* __restrict__ gamma, float* __restrict__ out)
{
    __shared__ alignas(16) unsigned char Pl[2][2][8192];  // [parity][tile][64m x 128B]
    __shared__ float lred[4][4][16];   // [kt][mt][lm]

    const int tid  = threadIdx.x;
    const int wave = tid >> 6;
    const int lane = tid & 63;
    const int g    = lane >> 4;
    const int lm   = lane & 15;
    const int bid  = blockIdx.x;
    const int b    = bid & 3;
    const int m0   = (bid >> 2) * 64;
    const int kt   = wave & 3;
    const int mtA  = (wave >> 2) * 2;
    const unsigned swz = (unsigned)(lm & 7) << 4;

    const bf16x8 qfA = *reinterpret_cast<const bf16x8*>(
        qb + ((size_t)b * NPOS + m0 + 16 * mtA + lm) * DQK + 8 * g);
    const bf16x8 qfB = *reinterpret_cast<const bf16x8*>(
        qb + ((size_t)b * NPOS + m0 + 16 * mtA + 16 + lm) * DQK + 8 * g);

    const __hip_bfloat16* kbb = kb + (size_t)b * NPOS * DQK;
    const int koff0 = (16 * kt + lm) * DQK + 8 * g;           // + t*2048
    const __hip_bfloat16* vbb = vb + (size_t)b * 16 * 64 * 1024;
    int vfb[4];                                                // + t*1024
    #pragma unroll
    for (int cti = 0; cti < 2; ++cti)
        #pragma unroll
        for (int kc = 0; kc < 2; ++kc)
            vfb[2 * cti + kc] = (2 * wave + cti) * 65536 + kc * 512 + lm * 32 + 8 * g;

    const unsigned wbA = (unsigned)(16 * mtA + lm) * 128
                       + (((unsigned)(32 * kt + 8 * g)) ^ swz);
    const unsigned wbB = wbA + 16 * 128;

    unsigned char* P0 = &Pl[0][0][0];
    unsigned char* P1 = &Pl[1][0][0];

    f32x4 acc[2][4];
    #pragma unroll
    for (int i = 0; i < 2; ++i)
        #pragma unroll
        for (int j = 0; j < 4; ++j) acc[i][j] = (f32x4){0.f, 0.f, 0.f, 0.f};
    float lsA = 0.f, lsB = 0.f;

#define LOADK(dst, tk_) \
    dst = *reinterpret_cast<const bf16x8*>(kbb + koff0 + (tk_) * 2048);

#define LOADV4(dst, tv_) { \
    _Pragma("unroll") for (int f = 0; f < 4; ++f) \
        dst[f] = *reinterpret_cast<const bf16x8*>(vbb + vfb[f] + (tv_) * 1024); }

#define QKW(KU, PW) { \
    f32x4 z = {0.f, 0.f, 0.f, 0.f}; \
    f32x4 sA = __builtin_amdgcn_mfma_f32_16x16x32_bf16(KU, qfA, z, 0, 0, 0); \
    f32x4 sB = __builtin_amdgcn_mfma_f32_16x16x32_bf16(KU, qfB, z, 0, 0, 0); \
    { float p0 = __expf(sA[0] - SHIFT), p1 = __expf(sA[1] - SHIFT); \
      float p2 = __expf(sA[2] - SHIFT), p3 = __expf(sA[3] - SHIFT); \
      lsA += (p0 + p1) + (p2 + p3); \
      uint2 w; w.x = pack_bf2(p0, p1); w.y = pack_bf2(p2, p3); \
      *reinterpret_cast<uint2*>((PW) + wbA) = w; } \
    { float p0 = __expf(sB[0] - SHIFT), p1 = __expf(sB[1] - SHIFT); \
      float p2 = __expf(sB[2] - SHIFT), p3 = __expf(sB[3] - SHIFT); \
      lsB += (p0 + p1) + (p2 + p3); \
      uint2 w; w.x = pack_bf2(p0, p1); w.y = pack_bf2(p2, p3); \
      *reinterpret_cast<uint2*>((PW) + wbB) = w; } }

#define PVt(PRb, VR) { \
    bf16x8 pf[4]; \
    _Pragma("unroll") for (int kc = 0; kc < 2; ++kc) { \
        _Pragma("unroll") for (int mt = 0; mt < 4; ++mt) \
            pf[mt] = *reinterpret_cast<const bf16x8*>( \
                (PRb) + (unsigned)(16 * mt + lm) * 128 \
                      + (((unsigned)(kc * 64 + 16 * g)) ^ swz)); \
        __builtin_amdgcn_s_setprio(1); \
        _Pragma("unroll") for (int cti = 0; cti < 2; ++cti) \
            _Pragma("unroll") for (int mt = 0; mt < 4; ++mt) \
                acc[cti][mt] = __builtin_amdgcn_mfma_f32_16x16x32_bf16( \
                    VR[2 * cti + kc], pf[mt], acc[cti][mt], 0, 0, 0); \
        __builtin_amdgcn_s_setprio(0); } }

// Phase body: t_ = first PV tile of this phase (even). PV(t_, t_+1) from PR;
// QK(t_+2, t_+3) -> PW; prefetch V(t_+2, t_+3) and K(t_+4, t_+5).
#define BODY2(t_, PR, PW, VRa, VRb, VLa, VLb, KU0, KU1, KL0, KL1) { \
    LOADV4(VLa, (t_) + 2); \
    LOADV4(VLb, (t_) + 3); \
    { int tk = (t_) + 4; if (tk > 63) tk = 63; LOADK(KL0, tk); } \
    { int tk = (t_) + 5; if (tk > 63) tk = 63; LOADK(KL1, tk); } \
    QKW(KU0, PW); \
    QKW(KU1, (PW) + 8192); \
    PVt(PR, VRa); \
    PVt((PR) + 8192, VRb); \
    lds_barrier(); }

    // prologue: K(0..3), V(0,1) in flight; S(0,1) -> P0
    bf16x8 k0, k1, k2, k3, vA0[4], vA1[4], vB0[4], vB1[4];
    LOADK(k0, 0); LOADK(k1, 1);
    LOADV4(vA0, 0); LOADV4(vA1, 1);
    LOADK(k2, 2); LOADK(k3, 3);
    QKW(k0, P0);
    QKW(k1, P0 + 8192);
    lds_barrier();

    // phases 0..30 (PV tiles 0..61), then final PV-only (62,63)
    for (int it = 0; it < 15; ++it) {
        const int t4 = 4 * it;
        BODY2(t4,     P0, P1, vA0, vA1, vB0, vB1, k2, k3, k0, k1);
        BODY2(t4 + 2, P1, P0, vB0, vB1, vA0, vA1, k0, k1, k2, k3);
    }
    BODY2(60, P0, P1, vA0, vA1, vB0, vB1, k2, k3, k0, k1);
    PVt(P1, vB0);
    PVt(P1 + 8192, vB1);

    // merge per-subtile l partials: reduce over g in-wave, over kt via LDS
    lsA += __shfl_xor(lsA, 16); lsA += __shfl_xor(lsA, 32);
    lsB += __shfl_xor(lsB, 16); lsB += __shfl_xor(lsB, 32);
    if (lane < 16) {
        lred[kt][mtA][lm]     = lsA;
        lred[kt][mtA + 1][lm] = lsB;
    }
    __syncthreads();

    float linv[4];
    #pragma unroll
    for (int mt = 0; mt < 4; ++mt)
        linv[mt] = 1.f / (lred[0][mt][lm] + lred[1][mt][lm]
                        + lred[2][mt][lm] + lred[3][mt][lm]);

    const float gmv = gamma[0];
    #pragma unroll
    for (int cti = 0; cti < 2; ++cti)
        #pragma unroll
        for (int mt = 0; mt < 4; ++mt)
            #pragma unroll
            for (int r = 0; r < 4; ++r) {
                int c = 32 * wave + 16 * cti + 4 * g + r;
                size_t idx = ((size_t)b * CH + c) * NPOS + m0 + 16 * mt + lm;
                out[idx] = gmv * (acc[cti][mt][r] * linv[mt]) + x[idx];
            }
#undef BODY2
#undef PVt
#undef QKW
#undef LOADV4
#undef LOADK
}

extern "C" void kernel_launch(void* const* d_in, const int* in_sizes, int n_in,
                              void* d_out, int out_size, void* d_ws, size_t ws_size,
                              hipStream_t stream) {
    const float* x  = (const float*)d_in[0];
    const float* Wq = (const float*)d_in[1];
    const float* bq = (const float*)d_in[2];
    const float* Wk = (const float*)d_in[3];
    const float* bk = (const float*)d_in[4];
    const float* Wv = (const float*)d_in[5];
    const float* bv = (const float*)d_in[6];
    const float* gm = (const float*)d_in[7];
    float* out = (float*)d_out;

    __hip_bfloat16* qbuf = (__hip_bfloat16*)d_ws;
    __hip_bfloat16* kbuf = qbuf + (size_t)BATCH * NPOS * DQK;
    __hip_bfloat16* vbuf = kbuf + (size_t)BATCH * NPOS * DQK;

    qkv_proj_mfma<<<dim3(NPOS / 32, BATCH), 256, 0, stream>>>(
        x, Wq, bq, Wk, bk, Wv, bv, qbuf, kbuf, vbuf);
    flash_pam_kernel<<<dim3(NPOS / 64 * BATCH), 512, 0, stream>>>(
        qbuf, kbuf, vbuf, x, gm, out);
}